// Round 10
// baseline (118.316 us; speedup 1.0000x reference)
//
#include <hip/hip_runtime.h>

// Detection post-process: softmax -> decode -> per-class LAZY NMS -> top-100.
// N=8 images, A=16384 anchors, C=21 classes (class 0 = background).
//
// Measurement ledger (nms dispatch, hw timestamps):
//   R7/R14 serial walk:        60.4us
//   R15 GROUP-RESOLVE walk:    45.6-49.0us  <- base (total 114.3)
//   TN=256: 121.6 | TN=1024: 70.0 | CAPC=1024: 80.3 | full kill-matrix: 96.2
//   in-kernel topk fence: 83.1 (buffer_wbl2/inv) | walk prefetch tweaks: NULL
// R15 counters: VALUBusy 24.5->15% at -20% time => residual nms (~35-40us) is
// stall-dominated FRONT phases: LDS-atomic histogram (hot bins), sort barriers,
// refill repetitions.
// R16: three independent front-phase cuts:
//   1. 4-way split histogram bins4[4][NBIN] (quarter same-address atomic serial-
//      ization; LDS +18KB free at 1 block/CU)
//   2. adaptive sort size S = next_pow2(max(T,64)): refills/small chunks sort
//      64-256 slots not 512 (S block-uniform -> uniform barriers; R12-verified
//      act-guard pattern)
//   3. TARGET 384->448 (fewer refills; sort cost now decoupled from CAPC)
// Exactness invariants (absmax 0.0 since R1):
//   - u64 key = (score_bits<<32)|~idx  => exact (score desc, idx asc) total order
//   - monotone bin(float bits) => bin-threshold selection is a key-order cut
//     (any TARGET: B = max(b1,b2) keeps suffix <= CAPC; smaller suffix just means
//      smaller chunk -- accept sequence unchanged)
//   - group scan == lazy NMS: only ACCEPTED candidates kill; order = sorted order;
//     na cap per accept; dead-vs-prev-chunk via accepted list only
//   - bitonic-S with zero padding sorts the T live keys identically for any S>=T
//   - division-free EXACT IoU predicate:
//     RN_f32(inter/un) > 0.45f  <=>  (double)inter > ((double)0.45f + 2^-26)*(double)un
//   - topk key = (score_bits<<32)|(0xFFFFFFFF-(flat_j+100)) => exact lax.top_k order

typedef unsigned long long u64;

#define N_IMG 8
#define A     16384
#define NCLS  21
#define NC    20
#define TOPK  100
#define PROB_THR 0.05f

#define TN     512         // 8 waves, 2/SIMD — measured optimum (R9/R12)
#define NSLOT  32          // scores per thread
#define NBIN   1152        // score-bit bins: (bits>>15)-31385 spans (0.05,1]
#define BINOFF 31385
#define CAPC   512         // chunk capacity — measured optimum (R13)
#define TARGET 448

#define PHYS(i) ((i) + ((i) >> 4))   // LDS u64 swizzle: breaks power-of-2 strides

#define MIDTHR ((double)0.45f + 0x1p-26)

#define AIDX(t_) ((tid << 2) + (((t_) >> 2) << 11) + ((t_) & 3))

__device__ __forceinline__ u64 pk(float v, int i) {
    return (v > 0.f) ? (((u64)__float_as_uint(v) << 32) | (u64)(unsigned)(~(unsigned)i)) : 0ull;
}
__device__ __forceinline__ float upv(u64 k) { return __uint_as_float((unsigned)(k >> 32)); }
__device__ __forceinline__ int   upi(u64 k) { return (int)(~(unsigned)k); }
__device__ __forceinline__ u64 umx(u64 a, u64 b) { return a > b ? a : b; }
__device__ __forceinline__ u64 umn(u64 a, u64 b) { return a < b ? a : b; }

// bitonic compare-exchange keep-rule for element i at stage (k,j):
// region (i&k)==0 sorts descending; lower partner ((i&j)==0) keeps max there.
__device__ __forceinline__ u64 bsel(u64 mine, u64 other, int i, int k, int j) {
    bool keep_max = ((i & k) == 0) == ((i & j) == 0);
    return keep_max ? umx(mine, other) : umn(mine, other);
}

__device__ __forceinline__ int binOf(float s) {
    int b = (int)(__float_as_uint(s) >> 15) - BINOFF;
    return b < 0 ? 0 : (b > NBIN - 1 ? NBIN - 1 : b);
}

// exact ref predicate: RN(inter/union) > 0.45f
__device__ __forceinline__ bool killp(float4 b, float ab, float4 s, float as_) {
    float lx = fmaxf(s.x, b.x), ly = fmaxf(s.y, b.y);
    float rx = fminf(s.z, b.z), ry = fminf(s.w, b.w);
    float iw = fmaxf(rx - lx, 0.f), ih = fmaxf(ry - ly, 0.f);
    float inter = iw * ih;
    float un = as_ + ab - inter;
    return (double)inter > MIDTHR * (double)un;
}

// Kernel 1: softmax + threshold -> scores[N][NC][A]; SSD decode -> clamped corner boxes.
__global__ __launch_bounds__(256) void preprocess_kernel(
    const float* __restrict__ cls, const float* __restrict__ reg,
    const float* __restrict__ anc, float4* __restrict__ boxes,
    float* __restrict__ scores) {
    __shared__ __align__(16) float lcls[256 * NCLS];
    const int tid = threadIdx.x;
    const int t = blockIdx.x * 256 + tid;

    const float4* src = (const float4*)(cls + (size_t)blockIdx.x * (256 * NCLS));
    float4* dst = (float4*)lcls;
    for (int i = tid; i < (256 * NCLS) / 4; i += 256) dst[i] = src[i];
    __syncthreads();

    const int n = t >> 14;
    const int a = t & (A - 1);
    const float* c = lcls + tid * NCLS;
    float z[NCLS];
    float m = -1e30f;
#pragma unroll
    for (int k = 0; k < NCLS; ++k) { z[k] = c[k]; m = fmaxf(m, z[k]); }
    float s = 0.f;
#pragma unroll
    for (int k = 0; k < NCLS; ++k) { z[k] = expf(z[k] - m); s += z[k]; }
    const float inv = 1.f / s;
#pragma unroll
    for (int k = 0; k < NC; ++k) {
        float p = z[k + 1] * inv;
        scores[(((size_t)n * NC + k) << 14) + a] = (p > PROB_THR) ? p : -1.f;
    }

    const float4 l4 = ((const float4*)reg)[t];
    const float4 an = ((const float4*)anc)[a];
    const float cx = an.x + l4.x * 0.1f * an.z;
    const float cy = an.y + l4.y * 0.1f * an.w;
    const float w  = an.z * expf(l4.z * 0.2f);
    const float h  = an.w * expf(l4.w * 0.2f);
    float x0 = fminf(fmaxf(cx - 0.5f * w, 0.f), 1.f);
    float y0 = fminf(fmaxf(cy - 0.5f * h, 0.f), 1.f);
    float x1 = fminf(fmaxf(cx + 0.5f * w, 0.f), 1.f);
    float y1 = fminf(fmaxf(cy + 0.5f * h, 0.f), 1.f);
    boxes[t] = make_float4(x0, y0, x1, y1);
}

// Kernel 2: one workgroup per (n, ci). hist-select -> sort-S -> group-resolve.
__global__ __launch_bounds__(TN) void nms_kernel(
    const float4* __restrict__ boxes, const float* __restrict__ scores,
    float* __restrict__ rows) {
    __shared__ int bins4[4][NBIN];     // split histogram (wave-pair copies)
    __shared__ u64 skey[PHYS(CAPC - 1) + 2];
    __shared__ __align__(16) float4 sbox[CAPC];
    __shared__ float sarea[CAPC];
    __shared__ u64 gm[8][64];          // group kill-matrix partials
    __shared__ u64 dm[8];              // group dead-vs-accepted partials
    __shared__ __align__(16) float4 abox[TOPK];   // accepted list
    __shared__ float aarea[TOPK];
    __shared__ u64 akey[TOPK];
    __shared__ u64 red8[TN / 64];
    __shared__ u64 bkey;
    __shared__ __align__(16) float4 bbox;
    __shared__ int sint[3];   // 0:B  1:cnt  2:degenerate

    const int blk = blockIdx.x, n = blk / NC, ci = blk % NC;
    const int tid = threadIdx.x, lane = tid & 63, w = tid >> 6;
    const float* gs = scores + ((size_t)blk << 14);
    const float4* gb = boxes + ((size_t)n << 14);
    float* grows = rows + (size_t)blk * 600;

    // scores -> registers (coalesced float4)
    float sc[NSLOT];
    const float4* gs4 = (const float4*)gs;
#pragma unroll
    for (int k = 0; k < NSLOT / 4; ++k) {
        float4 v = gs4[tid + (k << 9)];
        sc[k * 4 + 0] = v.x; sc[k * 4 + 1] = v.y; sc[k * 4 + 2] = v.z; sc[k * 4 + 3] = v.w;
    }

    int na = 0;
    u64 filter = ~0ull;
    bool done = false;

    while (!done && na < TOPK) {
        // ---- filtered histogram (4-way split: wave-pair w>>1 owns a copy) ----
        for (int i = tid; i < 4 * NBIN; i += TN) ((int*)bins4)[i] = 0;
        if (tid == 0) { sint[1] = 0; sint[2] = 0; }
        __syncthreads();
        int* mybins = bins4[w >> 1];
#pragma unroll
        for (int t = 0; t < NSLOT; ++t) {
            float s = sc[t];
            if (s > 0.f) {
                u64 kk = pk(s, AIDX(t));
                if (kk < filter) atomicAdd(&mybins[binOf(s)], 1);
            }
        }
        __syncthreads();

        // ---- select bin threshold B (wave0; sums the 4 histogram copies) ----
        if (tid < 64) {
            int lsum[18];
            int tot = 0;
#pragma unroll
            for (int k = 0; k < 18; ++k) {
                int b = tid * 18 + k;
                lsum[k] = bins4[0][b] + bins4[1][b] + bins4[2][b] + bins4[3][b];
                tot += lsum[k];
            }
            int pfx = tot;
#pragma unroll
            for (int off = 1; off < 64; off <<= 1) {
                int o = __shfl_up(pfx, off, 64);
                if (lane >= off) pfx += o;
            }
            const int totalAll = __shfl(pfx, 63, 64);
            const int sufAbove = totalAll - pfx;
            const int tgt = totalAll < TARGET ? totalAll : TARGET;
            int run = 0, b1 = -1, b2 = 1 << 30;
#pragma unroll
            for (int k = 17; k >= 0; --k) {
                run += lsum[k];
                int suf = sufAbove + run;
                int b = tid * 18 + k;
                if (suf >= tgt && b > b1) b1 = b;
                if (suf <= CAPC && b < b2) b2 = b;
            }
#pragma unroll
            for (int off = 1; off < 64; off <<= 1) {
                int o1 = __shfl_xor(b1, off, 64); if (o1 > b1) b1 = o1;
                int o2 = __shfl_xor(b2, off, 64); if (o2 < b2) b2 = o2;
            }
            if (lane == 0) {
                sint[0] = b1 > b2 ? b1 : b2;
                sint[2] = (b2 == (1 << 30)) ? 1 : 0;
            }
        }
        __syncthreads();
        const int B = sint[0];
        const int degen = sint[2];

        if (!degen) {
            // ---- compact keys of bins >= B (ballot-aggregated; order fixed by sort) ----
#pragma unroll
            for (int t = 0; t < NSLOT; ++t) {
                float s = sc[t];
                bool pred = false; u64 kk = 0ull;
                if (s > 0.f && binOf(s) >= B) {
                    kk = pk(s, AIDX(t));
                    pred = (kk < filter);
                }
                u64 m = __ballot(pred);
                if (m) {
                    int bse = 0;
                    if (lane == 0) bse = atomicAdd(&sint[1], __popcll(m));
                    bse = __shfl(bse, 0, 64);
                    if (pred) {
                        int sl = bse + __popcll(m & ((1ull << lane) - 1ull));
                        skey[PHYS(sl)] = kk;
                    }
                }
            }
            __syncthreads();
            const int T = sint[1];
            if (T == 0) break;                       // exhausted
            // adaptive sort size (block-uniform): smallest pow2 >= max(T, 64)
            int S = 64;
            while (S < T) S <<= 1;
            for (int i = T + tid; i < S; i += TN) skey[PHYS(i)] = 0ull;
            __syncthreads();

            // ---- hybrid bitonic sort-S desc on tid<S: shfl j<=32, LDS j>=64 ----
            {
                const bool act = (tid < S);
                u64 myk = act ? skey[PHYS(tid)] : 0ull;
                for (int kk2 = 2; kk2 <= S; kk2 <<= 1) {
                    for (int j = kk2 >> 1; j > 0; j >>= 1) {
                        if (j >= 64) {
                            if (act) skey[PHYS(tid)] = myk;
                            __syncthreads();
                            u64 other = act ? skey[PHYS(tid ^ j)] : 0ull;
                            __syncthreads();
                            if (act) myk = bsel(myk, other, tid, kk2, j);
                        } else {
                            u64 other = __shfl_xor(myk, j, 64);
                            if (act) myk = bsel(myk, other, tid, kk2, j);
                        }
                    }
                }
                if (act) skey[PHYS(tid)] = myk;   // last cross-read was pre-barrier: safe
            }
            __syncthreads();

            // ---- gather candidate boxes + areas in sorted order ----
            for (int p = tid; p < S; p += TN) {
                u64 kk = skey[PHYS(p)];
                if (kk) {
                    float4 b = gb[upi(kk)];
                    sbox[p] = b;
                    sarea[p] = (b.z - b.x) * (b.w - b.y);
                }
            }
            __syncthreads();

            // ---- group-resolve: 64-candidate groups, exact lazy-NMS order ----
            for (int base = 0; base < T && na < TOPK; base += 64) {
                const int cnt = (T - base < 64) ? (T - base) : 64;
                // this lane's candidate (garbage if lane >= cnt: masked below)
                const float4 cb = sbox[base + lane];
                const float ca = sarea[base + lane];
                __syncthreads();   // prev commits / gm readers done before overwrite

                // (A) dead vs previously-accepted: wave w covers q = w, w+8, ...
                bool d = false;
                for (int q = w; q < na; q += 8)
                    d = d || killp(cb, ca, abox[q], aarea[q]);
                u64 dball = __ballot(d);
                if (lane == 0) dm[w] = dball;

                // (B) intra-group matrix: wave w covers j in [8w, 8w+8)
                u64 pr = 0ull;
#pragma unroll
                for (int e = 0; e < 8; ++e) {
                    const int jj = (w << 3) + e;
                    bool kp = (jj < lane) && killp(cb, ca, sbox[base + jj], sarea[base + jj]);
                    pr |= ((u64)kp) << jj;
                }
                gm[w][lane] = pr;
                __syncthreads();

                // (C) OR partials: per-lane row; uniform dead mask
                u64 row = gm[0][lane];
#pragma unroll
                for (int q = 1; q < 8; ++q) row |= gm[q][lane];
                u64 dead = dm[0];
#pragma unroll
                for (int q = 1; q < 8; ++q) dead |= dm[q];

                // (D) alive-mask scan (all waves redundantly; cost ~ #accepts)
                u64 alive = ~dead;
                if (cnt < 64) alive &= (1ull << cnt) - 1ull;
                u64 gacc = 0ull;
                int naL = na;
                while (alive && naL < TOPK) {
                    const int g = (int)__builtin_ctzll(alive);
                    gacc |= 1ull << g;
                    ++naL;
                    const u64 colg = __ballot(((row >> g) & 1ull) != 0ull);
                    alive &= ~colg;
                    alive &= ~(1ull << g);
                }

                // (E) commit accepted (wave0 lanes; position via popcount prefix)
                if (w == 0 && ((gacc >> lane) & 1ull)) {
                    const int pos = na + (int)__popcll(gacc & ((1ull << lane) - 1ull));
                    abox[pos] = cb;
                    aarea[pos] = ca;
                    akey[pos] = skey[PHYS(base + lane)];
                }
                na = naL;   // uniform across block (redundant scan)
            }
            done = (na >= TOPK);
            if (!done) filter = skey[PHYS(T - 1)];   // chunk exhausted: next keys < min
            __syncthreads();                          // commits visible before reuse
        } else {
            // ---- degenerate (one bin > CAPC; never on real data): single extractions ----
            while (na < TOPK) {
                u64 best = 0ull;
#pragma unroll
                for (int t = 0; t < NSLOT; ++t) {
                    float s = sc[t];
                    if (s > 0.f) {
                        u64 kk = pk(s, AIDX(t));
                        if (kk < filter && kk > best) best = kk;
                    }
                }
#pragma unroll
                for (int off = 1; off < 64; off <<= 1) best = umx(best, __shfl_xor(best, off, 64));
                if (lane == 0) red8[w] = best;
                __syncthreads();
                if (tid == 0) {
                    u64 bb = red8[0];
#pragma unroll
                    for (int q = 1; q < TN / 64; ++q) bb = umx(bb, red8[q]);
                    bkey = bb;
                    if (bb) bbox = gb[upi(bb)];
                }
                __syncthreads();
                u64 kk = bkey;
                if (!kk) break;
                filter = kk;
                float4 cb = bbox;
                float ca = (cb.z - cb.x) * (cb.w - cb.y);
                bool kill = false;
                if (lane < na)      kill = killp(cb, ca, abox[lane], aarea[lane]);
                if (lane + 64 < na) kill = kill || killp(cb, ca, abox[lane + 64], aarea[lane + 64]);
                if (!__any(kill)) {
                    if (tid == 0) { abox[na] = cb; aarea[na] = ca; akey[na] = kk; }
                    ++na;           // uniform (all waves same data/math)
                }
                __syncthreads();
            }
            break;
        }
    }

    // ---- final rows write from accepted lists ----
    __syncthreads();
    if (tid < na) {
        float4 b = abox[tid];
        u64 kk = akey[tid];
        float* o = grows + tid * 6;
        o[0] = b.x; o[1] = b.y; o[2] = b.z; o[3] = b.w;
        o[4] = upv(kk); o[5] = (float)(ci + 1);
    }
    for (int j = na * 6 + tid; j < 600; j += TN) grows[j] = 0.f;
}

// Kernel 3: per image, bitonic sort of all 2048 padded candidate keys, gather top-100.
// key = (score_bits<<32) | (0xFFFFFFFF - flat_j), flat_j = (ci+1)*100 + pos. Exact
// lax.top_k order; zero-score selections are all-zero rows in both ref and ours.
// Hybrid shuffle/LDS bitonic, 2 keys/thread; only j>=128 via LDS.
__global__ __launch_bounds__(1024) void topk_kernel(
    const float* __restrict__ rows, float* __restrict__ out) {
    __shared__ u64 skey[PHYS(2047) + 2];
    const int n = blockIdx.x, tid = threadIdx.x;
    const float* base = rows + (size_t)n * (NC * 600);
    const int i0 = tid << 1, i1 = i0 | 1;

    u64 k0 = 0ull, k1 = 0ull;
    if (i0 < 2000) {
        int ci = i0 / 100, pos = i0 - ci * 100;
        float s = base[ci * 600 + pos * 6 + 4];
        k0 = ((u64)__float_as_uint(s) << 32) | (u64)(0xFFFFFFFFu - (unsigned)(i0 + 100));
    }
    if (i1 < 2000) {
        int ci = i1 / 100, pos = i1 - ci * 100;
        float s = base[ci * 600 + pos * 6 + 4];
        k1 = ((u64)__float_as_uint(s) << 32) | (u64)(0xFFFFFFFFu - (unsigned)(i1 + 100));
    }

    for (int kk2 = 2; kk2 <= 2048; kk2 <<= 1) {
        for (int j = kk2 >> 1; j > 0; j >>= 1) {
            if (j >= 128) {
                skey[PHYS(i0)] = k0; skey[PHYS(i1)] = k1;
                __syncthreads();
                u64 o0 = skey[PHYS(i0 ^ j)], o1 = skey[PHYS(i1 ^ j)];
                __syncthreads();
                k0 = bsel(k0, o0, i0, kk2, j);
                k1 = bsel(k1, o1, i1, kk2, j);
            } else if (j >= 2) {
                u64 o0 = __shfl_xor(k0, j >> 1, 64);
                u64 o1 = __shfl_xor(k1, j >> 1, 64);
                k0 = bsel(k0, o0, i0, kk2, j);
                k1 = bsel(k1, o1, i1, kk2, j);
            } else {
                bool mx0 = ((i0 & kk2) == 0);
                u64 mx = umx(k0, k1), mn = umn(k0, k1);
                k0 = mx0 ? mx : mn; k1 = mx0 ? mn : mx;
            }
        }
    }
    skey[PHYS(i0)] = k0; skey[PHYS(i1)] = k1;   // last cross-wave read was pre-barrier
    __syncthreads();

    if (tid < 600) {
        int r = tid / 6, f = tid - (tid / 6) * 6;
        u64 kk = skey[PHYS(r)];
        float v = 0.f;
        if ((unsigned)(kk >> 32) != 0u) {
            int e = (int)(0xFFFFFFFFu - (unsigned)kk) - 100;
            int ci = e / 100, pos = e - ci * 100;
            v = base[ci * 600 + pos * 6 + f];
        }
        out[(size_t)n * 600 + tid] = v;
    }
}

extern "C" void kernel_launch(void* const* d_in, const int* in_sizes, int n_in,
                              void* d_out, int out_size, void* d_ws, size_t ws_size,
                              hipStream_t stream) {
    const float* cls = (const float*)d_in[0];   // [8,16384,21]
    const float* reg = (const float*)d_in[1];   // [8,16384,4]
    const float* anc = (const float*)d_in[2];   // [16384,4]
    float* out = (float*)d_out;                 // [8,100,6]

    // ws layout (floats): boxes 524288 | scores 2621440 | rows 96000
    float* boxes  = (float*)d_ws;
    float* scores = boxes + (size_t)N_IMG * A * 4;
    float* rows   = scores + (size_t)N_IMG * NC * A;

    preprocess_kernel<<<(N_IMG * A) / 256, 256, 0, stream>>>(cls, reg, anc, (float4*)boxes, scores);
    nms_kernel<<<N_IMG * NC, TN, 0, stream>>>((const float4*)boxes, scores, rows);
    topk_kernel<<<N_IMG, 1024, 0, stream>>>(rows, out);
}

// Round 11
// 116.101 us; speedup vs baseline: 1.0191x; 1.0191x over previous
//
#include <hip/hip_runtime.h>

// Detection post-process: softmax -> decode -> per-class LAZY NMS -> top-100.
// N=8 images, A=16384 anchors, C=21 classes (class 0 = background).
//
// Measurement ledger (nms dispatch, hw timestamps):
//   R15 GROUP-RESOLVE walk:    45.6-49.0us  <- best (total 114.3); this file's base
//   R16 (split-hist + adaptive sort + TARGET448): 50.3-53.6 REGRESSED -> reverted
//     (TARGET=448 => S=512 on first chunk: adaptive sort dead path; hist atomics
//      exonerated: conflicts ~flat at 93k)
//   R7/R14 serial walk: 60.4 | TN=256: 121.6 | TN=1024: 70.0 | CAPC=1024: 80.3
//   full kill-matrix: 96.2 | in-kernel topk fence: 83.1 | walk prefetch: NULL
// Residual nms (~47us) is stall/barrier-dominated; sort-512 = 12 of ~25 per-chunk
// barriers.
// R17: R15 EXACT + one delta: sort LDS stages double-buffered (R11-verified
// pattern, absmax 0.0 there): write buf X -> barrier -> read X; next stage writes
// buf Y != X so no race with X's readers. 12 sort barriers -> 6.
// Exactness invariants (absmax 0.0 since R1):
//   - u64 key = (score_bits<<32)|~idx  => exact (score desc, idx asc) total order
//   - monotone bin(float bits) => bin-threshold selection is a key-order cut
//   - group scan == lazy NMS: only ACCEPTED candidates kill; order = sorted order;
//     na cap per accept; dead-vs-prev-chunk via accepted list only
//   - division-free EXACT IoU predicate:
//     RN_f32(inter/un) > 0.45f  <=>  (double)inter > ((double)0.45f + 2^-26)*(double)un
//   - topk key = (score_bits<<32)|(0xFFFFFFFF-(flat_j+100)) => exact lax.top_k order

typedef unsigned long long u64;

#define N_IMG 8
#define A     16384
#define NCLS  21
#define NC    20
#define TOPK  100
#define PROB_THR 0.05f

#define TN     512         // 8 waves, 2/SIMD — measured optimum (R9/R12)
#define NSLOT  32          // scores per thread
#define NBIN   1152        // score-bit bins: (bits>>15)-31385 spans (0.05,1]
#define BINOFF 31385
#define CAPC   512         // chunk capacity — measured optimum (R13)
#define TARGET 384         // measured optimum (R16: 448 not better)

#define PHYS(i) ((i) + ((i) >> 4))   // LDS u64 swizzle: breaks power-of-2 strides

#define MIDTHR ((double)0.45f + 0x1p-26)

#define AIDX(t_) ((tid << 2) + (((t_) >> 2) << 11) + ((t_) & 3))

__device__ __forceinline__ u64 pk(float v, int i) {
    return (v > 0.f) ? (((u64)__float_as_uint(v) << 32) | (u64)(unsigned)(~(unsigned)i)) : 0ull;
}
__device__ __forceinline__ float upv(u64 k) { return __uint_as_float((unsigned)(k >> 32)); }
__device__ __forceinline__ int   upi(u64 k) { return (int)(~(unsigned)k); }
__device__ __forceinline__ u64 umx(u64 a, u64 b) { return a > b ? a : b; }
__device__ __forceinline__ u64 umn(u64 a, u64 b) { return a < b ? a : b; }

// bitonic compare-exchange keep-rule for element i at stage (k,j):
// region (i&k)==0 sorts descending; lower partner ((i&j)==0) keeps max there.
__device__ __forceinline__ u64 bsel(u64 mine, u64 other, int i, int k, int j) {
    bool keep_max = ((i & k) == 0) == ((i & j) == 0);
    return keep_max ? umx(mine, other) : umn(mine, other);
}

__device__ __forceinline__ int binOf(float s) {
    int b = (int)(__float_as_uint(s) >> 15) - BINOFF;
    return b < 0 ? 0 : (b > NBIN - 1 ? NBIN - 1 : b);
}

// exact ref predicate: RN(inter/union) > 0.45f
__device__ __forceinline__ bool killp(float4 b, float ab, float4 s, float as_) {
    float lx = fmaxf(s.x, b.x), ly = fmaxf(s.y, b.y);
    float rx = fminf(s.z, b.z), ry = fminf(s.w, b.w);
    float iw = fmaxf(rx - lx, 0.f), ih = fmaxf(ry - ly, 0.f);
    float inter = iw * ih;
    float un = as_ + ab - inter;
    return (double)inter > MIDTHR * (double)un;
}

// Kernel 1: softmax + threshold -> scores[N][NC][A]; SSD decode -> clamped corner boxes.
__global__ __launch_bounds__(256) void preprocess_kernel(
    const float* __restrict__ cls, const float* __restrict__ reg,
    const float* __restrict__ anc, float4* __restrict__ boxes,
    float* __restrict__ scores) {
    __shared__ __align__(16) float lcls[256 * NCLS];
    const int tid = threadIdx.x;
    const int t = blockIdx.x * 256 + tid;

    const float4* src = (const float4*)(cls + (size_t)blockIdx.x * (256 * NCLS));
    float4* dst = (float4*)lcls;
    for (int i = tid; i < (256 * NCLS) / 4; i += 256) dst[i] = src[i];
    __syncthreads();

    const int n = t >> 14;
    const int a = t & (A - 1);
    const float* c = lcls + tid * NCLS;
    float z[NCLS];
    float m = -1e30f;
#pragma unroll
    for (int k = 0; k < NCLS; ++k) { z[k] = c[k]; m = fmaxf(m, z[k]); }
    float s = 0.f;
#pragma unroll
    for (int k = 0; k < NCLS; ++k) { z[k] = expf(z[k] - m); s += z[k]; }
    const float inv = 1.f / s;
#pragma unroll
    for (int k = 0; k < NC; ++k) {
        float p = z[k + 1] * inv;
        scores[(((size_t)n * NC + k) << 14) + a] = (p > PROB_THR) ? p : -1.f;
    }

    const float4 l4 = ((const float4*)reg)[t];
    const float4 an = ((const float4*)anc)[a];
    const float cx = an.x + l4.x * 0.1f * an.z;
    const float cy = an.y + l4.y * 0.1f * an.w;
    const float w  = an.z * expf(l4.z * 0.2f);
    const float h  = an.w * expf(l4.w * 0.2f);
    float x0 = fminf(fmaxf(cx - 0.5f * w, 0.f), 1.f);
    float y0 = fminf(fmaxf(cy - 0.5f * h, 0.f), 1.f);
    float x1 = fminf(fmaxf(cx + 0.5f * w, 0.f), 1.f);
    float y1 = fminf(fmaxf(cy + 0.5f * h, 0.f), 1.f);
    boxes[t] = make_float4(x0, y0, x1, y1);
}

// Kernel 2: one workgroup per (n, ci). hist-select -> sort-512 -> group-resolve.
__global__ __launch_bounds__(TN) void nms_kernel(
    const float4* __restrict__ boxes, const float* __restrict__ scores,
    float* __restrict__ rows) {
    __shared__ int bins[NBIN];
    __shared__ u64 skeyA[PHYS(CAPC - 1) + 2];   // sort double-buffer
    __shared__ u64 skeyB[PHYS(CAPC - 1) + 2];
    __shared__ __align__(16) float4 sbox[CAPC];
    __shared__ float sarea[CAPC];
    __shared__ u64 gm[8][64];          // group kill-matrix partials
    __shared__ u64 dm[8];              // group dead-vs-accepted partials
    __shared__ __align__(16) float4 abox[TOPK];   // accepted list
    __shared__ float aarea[TOPK];
    __shared__ u64 akey[TOPK];
    __shared__ u64 red8[TN / 64];
    __shared__ u64 bkey;
    __shared__ __align__(16) float4 bbox;
    __shared__ int sint[3];   // 0:B  1:cnt  2:degenerate

    const int blk = blockIdx.x, n = blk / NC, ci = blk % NC;
    const int tid = threadIdx.x, lane = tid & 63, w = tid >> 6;
    const float* gs = scores + ((size_t)blk << 14);
    const float4* gb = boxes + ((size_t)n << 14);
    float* grows = rows + (size_t)blk * 600;

    // scores -> registers (coalesced float4)
    float sc[NSLOT];
    const float4* gs4 = (const float4*)gs;
#pragma unroll
    for (int k = 0; k < NSLOT / 4; ++k) {
        float4 v = gs4[tid + (k << 9)];
        sc[k * 4 + 0] = v.x; sc[k * 4 + 1] = v.y; sc[k * 4 + 2] = v.z; sc[k * 4 + 3] = v.w;
    }

    int na = 0;
    u64 filter = ~0ull;
    bool done = false;

    while (!done && na < TOPK) {
        // ---- filtered histogram ----
        for (int i = tid; i < NBIN; i += TN) bins[i] = 0;
        if (tid == 0) { sint[1] = 0; sint[2] = 0; }
        __syncthreads();
#pragma unroll
        for (int t = 0; t < NSLOT; ++t) {
            float s = sc[t];
            if (s > 0.f) {
                u64 kk = pk(s, AIDX(t));
                if (kk < filter) atomicAdd(&bins[binOf(s)], 1);
            }
        }
        __syncthreads();

        // ---- select bin threshold B (wave0) ----
        if (tid < 64) {
            int lsum[18];
            int tot = 0;
#pragma unroll
            for (int k = 0; k < 18; ++k) { lsum[k] = bins[tid * 18 + k]; tot += lsum[k]; }
            int pfx = tot;
#pragma unroll
            for (int off = 1; off < 64; off <<= 1) {
                int o = __shfl_up(pfx, off, 64);
                if (lane >= off) pfx += o;
            }
            const int totalAll = __shfl(pfx, 63, 64);
            const int sufAbove = totalAll - pfx;
            const int tgt = totalAll < TARGET ? totalAll : TARGET;
            int run = 0, b1 = -1, b2 = 1 << 30;
#pragma unroll
            for (int k = 17; k >= 0; --k) {
                run += lsum[k];
                int suf = sufAbove + run;
                int b = tid * 18 + k;
                if (suf >= tgt && b > b1) b1 = b;
                if (suf <= CAPC && b < b2) b2 = b;
            }
#pragma unroll
            for (int off = 1; off < 64; off <<= 1) {
                int o1 = __shfl_xor(b1, off, 64); if (o1 > b1) b1 = o1;
                int o2 = __shfl_xor(b2, off, 64); if (o2 < b2) b2 = o2;
            }
            if (lane == 0) {
                sint[0] = b1 > b2 ? b1 : b2;
                sint[2] = (b2 == (1 << 30)) ? 1 : 0;
            }
        }
        __syncthreads();
        const int B = sint[0];
        const int degen = sint[2];

        if (!degen) {
            // ---- compact keys of bins >= B into skeyA ----
#pragma unroll
            for (int t = 0; t < NSLOT; ++t) {
                float s = sc[t];
                bool pred = false; u64 kk = 0ull;
                if (s > 0.f && binOf(s) >= B) {
                    kk = pk(s, AIDX(t));
                    pred = (kk < filter);
                }
                u64 m = __ballot(pred);
                if (m) {
                    int bse = 0;
                    if (lane == 0) bse = atomicAdd(&sint[1], __popcll(m));
                    bse = __shfl(bse, 0, 64);
                    if (pred) {
                        int sl = bse + __popcll(m & ((1ull << lane) - 1ull));
                        skeyA[PHYS(sl)] = kk;
                    }
                }
            }
            __syncthreads();
            const int T = sint[1];
            if (T == 0) break;                       // exhausted
            for (int i = T + tid; i < CAPC; i += TN) skeyA[PHYS(i)] = 0ull;
            __syncthreads();

            // ---- hybrid bitonic sort-512 desc: shfl j<=32; LDS j>=64 double-
            // buffered, ONE barrier/stage (R11-verified): stage writes buf X,
            // barrier, reads X; next stage writes Y!=X -> no race with X readers ----
            u64* wb = skeyB;
            {
                u64 myk = skeyA[PHYS(tid)];
                for (int kk2 = 2; kk2 <= CAPC; kk2 <<= 1) {
                    for (int j = kk2 >> 1; j > 0; j >>= 1) {
                        u64 other;
                        if (j >= 64) {
                            wb[PHYS(tid)] = myk;
                            __syncthreads();
                            other = wb[PHYS(tid ^ j)];
                            wb = (wb == skeyB) ? skeyA : skeyB;
                        } else {
                            other = __shfl_xor(myk, j, 64);
                        }
                        myk = bsel(myk, other, tid, kk2, j);
                    }
                }
                // 6 LDS stages -> wb == skeyB; skeyB's last cross-reads preceded
                // the stage-6 barrier -> safe to overwrite, one barrier publishes.
                wb[PHYS(tid)] = myk;
            }
            __syncthreads();
            u64* skf = wb;             // == skeyB: final sorted keys

            // ---- gather candidate boxes + areas in sorted order ----
            for (int p = tid; p < CAPC; p += TN) {
                u64 kk = skf[PHYS(p)];
                if (kk) {
                    float4 b = gb[upi(kk)];
                    sbox[p] = b;
                    sarea[p] = (b.z - b.x) * (b.w - b.y);
                }
            }
            __syncthreads();

            // ---- group-resolve: 64-candidate groups, exact lazy-NMS order ----
            for (int base = 0; base < T && na < TOPK; base += 64) {
                const int cnt = (T - base < 64) ? (T - base) : 64;
                // this lane's candidate (garbage if lane >= cnt: masked below)
                const float4 cb = sbox[base + lane];
                const float ca = sarea[base + lane];
                __syncthreads();   // prev commits / gm readers done before overwrite

                // (A) dead vs previously-accepted: wave w covers q = w, w+8, ...
                bool d = false;
                for (int q = w; q < na; q += 8)
                    d = d || killp(cb, ca, abox[q], aarea[q]);
                u64 dball = __ballot(d);
                if (lane == 0) dm[w] = dball;

                // (B) intra-group matrix: wave w covers j in [8w, 8w+8)
                u64 pr = 0ull;
#pragma unroll
                for (int e = 0; e < 8; ++e) {
                    const int jj = (w << 3) + e;
                    bool kp = (jj < lane) && killp(cb, ca, sbox[base + jj], sarea[base + jj]);
                    pr |= ((u64)kp) << jj;
                }
                gm[w][lane] = pr;
                __syncthreads();

                // (C) OR partials: per-lane row; uniform dead mask
                u64 row = gm[0][lane];
#pragma unroll
                for (int q = 1; q < 8; ++q) row |= gm[q][lane];
                u64 dead = dm[0];
#pragma unroll
                for (int q = 1; q < 8; ++q) dead |= dm[q];

                // (D) alive-mask scan (all waves redundantly; cost ~ #accepts)
                u64 alive = ~dead;
                if (cnt < 64) alive &= (1ull << cnt) - 1ull;
                u64 gacc = 0ull;
                int naL = na;
                while (alive && naL < TOPK) {
                    const int g = (int)__builtin_ctzll(alive);
                    gacc |= 1ull << g;
                    ++naL;
                    const u64 colg = __ballot(((row >> g) & 1ull) != 0ull);
                    alive &= ~colg;
                    alive &= ~(1ull << g);
                }

                // (E) commit accepted (wave0 lanes; position via popcount prefix)
                if (w == 0 && ((gacc >> lane) & 1ull)) {
                    const int pos = na + (int)__popcll(gacc & ((1ull << lane) - 1ull));
                    abox[pos] = cb;
                    aarea[pos] = ca;
                    akey[pos] = skf[PHYS(base + lane)];
                }
                na = naL;   // uniform across block (redundant scan)
            }
            done = (na >= TOPK);
            if (!done) filter = skf[PHYS(T - 1)];    // chunk exhausted: next keys < min
            __syncthreads();                          // commits visible before reuse
        } else {
            // ---- degenerate (one bin > CAPC; never on real data): single extractions ----
            while (na < TOPK) {
                u64 best = 0ull;
#pragma unroll
                for (int t = 0; t < NSLOT; ++t) {
                    float s = sc[t];
                    if (s > 0.f) {
                        u64 kk = pk(s, AIDX(t));
                        if (kk < filter && kk > best) best = kk;
                    }
                }
#pragma unroll
                for (int off = 1; off < 64; off <<= 1) best = umx(best, __shfl_xor(best, off, 64));
                if (lane == 0) red8[w] = best;
                __syncthreads();
                if (tid == 0) {
                    u64 bb = red8[0];
#pragma unroll
                    for (int q = 1; q < TN / 64; ++q) bb = umx(bb, red8[q]);
                    bkey = bb;
                    if (bb) bbox = gb[upi(bb)];
                }
                __syncthreads();
                u64 kk = bkey;
                if (!kk) break;
                filter = kk;
                float4 cb = bbox;
                float ca = (cb.z - cb.x) * (cb.w - cb.y);
                bool kill = false;
                if (lane < na)      kill = killp(cb, ca, abox[lane], aarea[lane]);
                if (lane + 64 < na) kill = kill || killp(cb, ca, abox[lane + 64], aarea[lane + 64]);
                if (!__any(kill)) {
                    if (tid == 0) { abox[na] = cb; aarea[na] = ca; akey[na] = kk; }
                    ++na;           // uniform (all waves same data/math)
                }
                __syncthreads();
            }
            break;
        }
    }

    // ---- final rows write from accepted lists ----
    __syncthreads();
    if (tid < na) {
        float4 b = abox[tid];
        u64 kk = akey[tid];
        float* o = grows + tid * 6;
        o[0] = b.x; o[1] = b.y; o[2] = b.z; o[3] = b.w;
        o[4] = upv(kk); o[5] = (float)(ci + 1);
    }
    for (int j = na * 6 + tid; j < 600; j += TN) grows[j] = 0.f;
}

// Kernel 3: per image, bitonic sort of all 2048 padded candidate keys, gather top-100.
// key = (score_bits<<32) | (0xFFFFFFFF - flat_j), flat_j = (ci+1)*100 + pos. Exact
// lax.top_k order; zero-score selections are all-zero rows in both ref and ours.
// Hybrid shuffle/LDS bitonic, 2 keys/thread; only j>=128 via LDS.
__global__ __launch_bounds__(1024) void topk_kernel(
    const float* __restrict__ rows, float* __restrict__ out) {
    __shared__ u64 skey[PHYS(2047) + 2];
    const int n = blockIdx.x, tid = threadIdx.x;
    const float* base = rows + (size_t)n * (NC * 600);
    const int i0 = tid << 1, i1 = i0 | 1;

    u64 k0 = 0ull, k1 = 0ull;
    if (i0 < 2000) {
        int ci = i0 / 100, pos = i0 - ci * 100;
        float s = base[ci * 600 + pos * 6 + 4];
        k0 = ((u64)__float_as_uint(s) << 32) | (u64)(0xFFFFFFFFu - (unsigned)(i0 + 100));
    }
    if (i1 < 2000) {
        int ci = i1 / 100, pos = i1 - ci * 100;
        float s = base[ci * 600 + pos * 6 + 4];
        k1 = ((u64)__float_as_uint(s) << 32) | (u64)(0xFFFFFFFFu - (unsigned)(i1 + 100));
    }

    for (int kk2 = 2; kk2 <= 2048; kk2 <<= 1) {
        for (int j = kk2 >> 1; j > 0; j >>= 1) {
            if (j >= 128) {
                skey[PHYS(i0)] = k0; skey[PHYS(i1)] = k1;
                __syncthreads();
                u64 o0 = skey[PHYS(i0 ^ j)], o1 = skey[PHYS(i1 ^ j)];
                __syncthreads();
                k0 = bsel(k0, o0, i0, kk2, j);
                k1 = bsel(k1, o1, i1, kk2, j);
            } else if (j >= 2) {
                u64 o0 = __shfl_xor(k0, j >> 1, 64);
                u64 o1 = __shfl_xor(k1, j >> 1, 64);
                k0 = bsel(k0, o0, i0, kk2, j);
                k1 = bsel(k1, o1, i1, kk2, j);
            } else {
                bool mx0 = ((i0 & kk2) == 0);
                u64 mx = umx(k0, k1), mn = umn(k0, k1);
                k0 = mx0 ? mx : mn; k1 = mx0 ? mn : mx;
            }
        }
    }
    skey[PHYS(i0)] = k0; skey[PHYS(i1)] = k1;   // last cross-wave read was pre-barrier
    __syncthreads();

    if (tid < 600) {
        int r = tid / 6, f = tid - (tid / 6) * 6;
        u64 kk = skey[PHYS(r)];
        float v = 0.f;
        if ((unsigned)(kk >> 32) != 0u) {
            int e = (int)(0xFFFFFFFFu - (unsigned)kk) - 100;
            int ci = e / 100, pos = e - ci * 100;
            v = base[ci * 600 + pos * 6 + f];
        }
        out[(size_t)n * 600 + tid] = v;
    }
}

extern "C" void kernel_launch(void* const* d_in, const int* in_sizes, int n_in,
                              void* d_out, int out_size, void* d_ws, size_t ws_size,
                              hipStream_t stream) {
    const float* cls = (const float*)d_in[0];   // [8,16384,21]
    const float* reg = (const float*)d_in[1];   // [8,16384,4]
    const float* anc = (const float*)d_in[2];   // [16384,4]
    float* out = (float*)d_out;                 // [8,100,6]

    // ws layout (floats): boxes 524288 | scores 2621440 | rows 96000
    float* boxes  = (float*)d_ws;
    float* scores = boxes + (size_t)N_IMG * A * 4;
    float* rows   = scores + (size_t)N_IMG * NC * A;

    preprocess_kernel<<<(N_IMG * A) / 256, 256, 0, stream>>>(cls, reg, anc, (float4*)boxes, scores);
    nms_kernel<<<N_IMG * NC, TN, 0, stream>>>((const float4*)boxes, scores, rows);
    topk_kernel<<<N_IMG, 1024, 0, stream>>>(rows, out);
}